// Round 1
// baseline (172.683 us; speedup 1.0000x reference)
//
#include <hip/hip_runtime.h>
#include <hip/hip_bf16.h>
#include <stdint.h>

// Problem constants (B=1)
#define NN   256     // MSA depth (contraction K of GEMM1)
#define LL   192
#define JJ   32
#define MDIM 6144    // L*J
#define D2   1024    // J*J
#define FF   128     // n_feat_out

typedef __bf16 bf16x8 __attribute__((ext_vector_type(8)));
typedef float  f32x4  __attribute__((ext_vector_type(4)));

#define MFMA16(a, b, c) __builtin_amdgcn_mfma_f32_16x16x32_bf16(a, b, c, 0, 0, 0)

__device__ __forceinline__ void gload_lds16(const void* g, void* l) {
  __builtin_amdgcn_global_load_lds(
      (__attribute__((address_space(1))) void*)(g),
      (__attribute__((address_space(3))) void*)(l),
      16, 0, 0);
}

// ---------------------------------------------------------------------------
// Prep 1: transpose [256][6144] f32 -> [6144][256] bf16 (K-contiguous rows)
// ---------------------------------------------------------------------------
__global__ void transpose_to_bf16(const float* __restrict__ src,
                                  __bf16* __restrict__ dst) {
  __shared__ float tile[32][33];
  const int m0 = blockIdx.x * 32;   // 192 blocks
  const int k0 = blockIdx.y * 32;   // 8 blocks
  const int tx = threadIdx.x, ty = threadIdx.y;  // 32 x 8
#pragma unroll
  for (int i = 0; i < 32; i += 8)
    tile[ty + i][tx] = src[(size_t)(k0 + ty + i) * MDIM + m0 + tx];
  __syncthreads();
#pragma unroll
  for (int i = 0; i < 32; i += 8)
    dst[(size_t)(m0 + ty + i) * NN + k0 + tx] = (__bf16)tile[tx][ty + i];
}

// ---------------------------------------------------------------------------
// Prep 2: WaT[f][k] = bf16(a2[k]*W[k][f]);  S[f]=sum_k WaT; T[f]=b2@W + b
// ---------------------------------------------------------------------------
__global__ void prep_w(const float* __restrict__ W, const float* __restrict__ a2,
                       const float* __restrict__ b2, const float* __restrict__ bias,
                       __bf16* __restrict__ WaT, float* __restrict__ S,
                       float* __restrict__ T) {
  const int f = blockIdx.x;       // 128 blocks
  const int t = threadIdx.x;      // 256 threads
  float s = 0.f, tt = 0.f;
#pragma unroll
  for (int k = t; k < D2; k += 256) {
    float wv = W[(size_t)k * FF + f];
    __bf16 wa = (__bf16)(a2[k] * wv);
    WaT[(size_t)f * D2 + k] = wa;
    s += (float)wa;
    tt += b2[k] * wv;
  }
#pragma unroll
  for (int off = 32; off; off >>= 1) {
    s += __shfl_xor(s, off);
    tt += __shfl_xor(tt, off);
  }
  __shared__ float ss[4], st[4];
  const int wv_ = t >> 6, ln = t & 63;
  if (ln == 0) { ss[wv_] = s; st[wv_] = tt; }
  __syncthreads();
  if (t == 0) {
    S[f] = ss[0] + ss[1] + ss[2] + ss[3];
    T[f] = st[0] + st[1] + st[2] + st[3] + bias[f];
  }
}

// ---------------------------------------------------------------------------
// Fused: GEMM1 (128x128 tile, K=256) + per-32x32-block LN stats + GEMM2(1024->128)
// C row m = i*32+j, col n = l*32+mm. LN row r = i_local*4 + l_local (0..15).
// out = rstd*(x@Wa - mean*S) + T
// ---------------------------------------------------------------------------
__global__ __launch_bounds__(256)
void fused_coevol(const __bf16* __restrict__ At, const __bf16* __restrict__ Bt,
                  const __bf16* __restrict__ WaT, const float* __restrict__ S,
                  const float* __restrict__ T, float* __restrict__ out) {
  __shared__ uint8_t lds[32768];      // GEMM1 stage (16K A + 16K B) then Xs (16x1024 bf16)
  __shared__ float mean_s[16], rstd_s[16];

  const int tid = threadIdx.x;
  const int w = tid >> 6;          // wave 0..3
  const int lane = tid & 63;
  const int q = lane >> 4;         // quad
  const int c = lane & 15;
  const int bx = blockIdx.x, by = blockIdx.y;
  const int m0 = bx * 128, n0 = by * 128;

  uint8_t* As = lds;
  uint8_t* Bs = lds + 16384;

  // staging lane decomposition: 8 lanes per 128B row (BK=64 bf16)
  const int l8 = lane & 7;
  const int r8 = lane >> 3;
  const int gsw = l8 ^ r8;         // XOR-swizzled source 16B-group

  f32x4 acc[4][4];
#pragma unroll
  for (int i = 0; i < 4; ++i)
#pragma unroll
    for (int j = 0; j < 4; ++j)
      acc[i][j] = (f32x4){0.f, 0.f, 0.f, 0.f};

  const int mbase = (w & 1) * 64;
  const int nbase = (w >> 1) * 64;

  // ---------------- GEMM1 K-loop: 4 chunks of BK=64 ----------------
  for (int kb = 0; kb < 4; ++kb) {
    __syncthreads();
#pragma unroll
    for (int s = 0; s < 4; ++s) {
      const int mrow = s * 32 + w * 8 + r8;   // 0..127, disjoint per wave
      const uint8_t* ga = (const uint8_t*)At +
          (((size_t)(m0 + mrow)) * NN + kb * 64 + gsw * 8) * 2;
      const uint8_t* gb = (const uint8_t*)Bt +
          (((size_t)(n0 + mrow)) * NN + kb * 64 + gsw * 8) * 2;
      gload_lds16(ga, As + (s * 32 + w * 8) * 128);
      gload_lds16(gb, Bs + (s * 32 + w * 8) * 128);
    }
    __syncthreads();
#pragma unroll
    for (int ks = 0; ks < 2; ++ks) {
      bf16x8 a[4], b[4];
#pragma unroll
      for (int t = 0; t < 4; ++t) {
        const int mr = mbase + t * 16 + c;
        const int slot = (ks * 4 + q) ^ (lane & 7);
        a[t] = *(const bf16x8*)(As + mr * 128 + slot * 16);
        const int nr = nbase + t * 16 + c;
        b[t] = *(const bf16x8*)(Bs + nr * 128 + slot * 16);
      }
#pragma unroll
      for (int ti = 0; ti < 4; ++ti)
#pragma unroll
        for (int tj = 0; tj < 4; ++tj)
          acc[ti][tj] = MFMA16(a[ti], b[tj], acc[ti][tj]);
    }
  }

  // ---------------- LN stats + raw-bf16 round-trip to LDS A-layout ----------------
  __syncthreads();   // all staging reads done; lds becomes Xs[16][1024]
  const int i_hi = w & 1, l_hi = w >> 1;
#pragma unroll
  for (int ab = 0; ab < 2; ++ab) {          // i_local low bit
#pragma unroll
    for (int cb = 0; cb < 2; ++cb) {        // l_local low bit
      float s1 = 0.f, s2 = 0.f;
#pragma unroll
      for (int dti = 0; dti < 2; ++dti)
#pragma unroll
        for (int dtj = 0; dtj < 2; ++dtj)
#pragma unroll
          for (int reg = 0; reg < 4; ++reg) {
            const float v = acc[ab * 2 + dti][cb * 2 + dtj][reg];
            s1 += v; s2 += v * v;
          }
#pragma unroll
      for (int off = 32; off; off >>= 1) {
        s1 += __shfl_xor(s1, off);
        s2 += __shfl_xor(s2, off);
      }
      const float mean = s1 * (1.0f / 1024.0f);
      const float var = s2 * (1.0f / 1024.0f) - mean * mean;
      const float rstd = rsqrtf(var + 1e-5f);
      const int r = (i_hi * 2 + ab) * 4 + (l_hi * 2 + cb);
      if (lane == 0) { mean_s[r] = mean; rstd_s[r] = rstd; }
      const int r7 = r & 7;
#pragma unroll
      for (int dti = 0; dti < 2; ++dti)
#pragma unroll
        for (int dtj = 0; dtj < 2; ++dtj)
#pragma unroll
          for (int reg = 0; reg < 4; ++reg) {
            const int j = dti * 16 + q * 4 + reg;   // C-row within 32-block
            const int mm = dtj * 16 + c;            // C-col within 32-block
            const int k = j * 32 + mm;
            const int g = k >> 3;
            const int off = r * 2048 + ((g ^ r7) * 16) + (mm & 7) * 2;
            *(__bf16*)(lds + off) = (__bf16)acc[ab * 2 + dti][cb * 2 + dtj][reg];
          }
    }
  }
  __syncthreads();

  // ---------------- GEMM2: Xs(16x1024) @ WaT^T -> 16x128 ----------------
  f32x4 acc2[2];
  acc2[0] = (f32x4){0.f, 0.f, 0.f, 0.f};
  acc2[1] = (f32x4){0.f, 0.f, 0.f, 0.f};
  const int fb = w * 32;
  const __bf16* wrow0 = WaT + (size_t)(fb + c) * D2;
  const __bf16* wrow1 = WaT + (size_t)(fb + 16 + c) * D2;
  const int r7 = lane & 7;   // row = c, (c&7)
#pragma unroll 4
  for (int kstep = 0; kstep < 32; ++kstep) {
    const int g = kstep * 4 + q;
    const bf16x8 av = *(const bf16x8*)(lds + c * 2048 + ((g ^ r7) * 16));
    const bf16x8 b0 = *(const bf16x8*)(wrow0 + kstep * 32 + q * 8);
    const bf16x8 b1 = *(const bf16x8*)(wrow1 + kstep * 32 + q * 8);
    acc2[0] = MFMA16(av, b0, acc2[0]);
    acc2[1] = MFMA16(av, b1, acc2[1]);
  }

  // ---------------- epilogue: affine + store ----------------
  const float S0 = S[fb + c], T0 = T[fb + c];
  const float S1 = S[fb + 16 + c], T1 = T[fb + 16 + c];
#pragma unroll
  for (int reg = 0; reg < 4; ++reg) {
    const int r = q * 4 + reg;           // LN row 0..15
    const float mean = mean_s[r], rstd = rstd_s[r];
    const int i = bx * 4 + (r >> 2);
    const int l = by * 4 + (r & 3);
    const size_t base = ((size_t)i * LL + l) * FF;
    out[base + fb + c]      = rstd * (acc2[0][reg] - mean * S0) + T0;
    out[base + fb + 16 + c] = rstd * (acc2[1][reg] - mean * S1) + T1;
  }
}

// ---------------------------------------------------------------------------
extern "C" void kernel_launch(void* const* d_in, const int* in_sizes, int n_in,
                              void* d_out, int out_size, void* d_ws, size_t ws_size,
                              hipStream_t stream) {
  const float* x_down   = (const float*)d_in[0];
  const float* x_down_w = (const float*)d_in[1];
  const float* a2       = (const float*)d_in[2];
  const float* b2       = (const float*)d_in[3];
  const float* W        = (const float*)d_in[4];
  const float* bias     = (const float*)d_in[5];
  float* out = (float*)d_out;

  uint8_t* ws = (uint8_t*)d_ws;
  __bf16* At  = (__bf16*)(ws);                 // 6144*256*2 = 3145728 B
  __bf16* Bt  = (__bf16*)(ws + 3145728);       // 3145728 B
  __bf16* WaT = (__bf16*)(ws + 6291456);       // 128*1024*2 = 262144 B
  float*  S   = (float*)(ws + 6553600);        // 512 B
  float*  T   = (float*)(ws + 6554112);        // 512 B

  transpose_to_bf16<<<dim3(192, 8), dim3(32, 8), 0, stream>>>(x_down, At);
  transpose_to_bf16<<<dim3(192, 8), dim3(32, 8), 0, stream>>>(x_down_w, Bt);
  prep_w<<<dim3(128), dim3(256), 0, stream>>>(W, a2, b2, bias, WaT, S, T);
  fused_coevol<<<dim3(48, 48), dim3(256), 0, stream>>>(At, Bt, WaT, S, T, out);
}